// Round 1
// baseline (384.130 us; speedup 1.0000x reference)
//
#include <hip/hip_runtime.h>
#include <cstdint>
#include <cstddef>
#include <cfloat>
#include <climits>

#define D_DIM   1024
#define P_DIM   2048
#define NB      2
#define NR      128
#define NS      128
#define KTOP    4
#define E_DIM   8192
#define ANG_EPS 1e-8f
#define M_PAIR  768   // 128 ref_t + 128 ref_s + 512 H rows
#define N_PAIR  768   // 3 pairs * (128 Sh_t + 128 Sh_s)

__device__ __forceinline__ float dot4(float4 a, float4 b) {
  return a.x * b.x + a.y * b.y + a.z * b.z + a.w * b.w;
}

__device__ __forceinline__ float huber(float e) {
  float ae = fabsf(e);
  return ae <= 1.0f ? 0.5f * e * e : ae - 0.5f;
}

__device__ __forceinline__ bool better(float va, int ia, float vb, int ib) {
  return (va > vb) || (va == vb && ia < ib);
}

// valid result on thread 0 only; scratch must hold blockDim/64 floats
__device__ __forceinline__ float block_reduce_sum(float v, float* scratch) {
  #pragma unroll
  for (int o = 32; o > 0; o >>= 1) v += __shfl_down(v, o);
  __syncthreads();                       // protect scratch from prior use
  if ((threadIdx.x & 63) == 0) scratch[threadIdx.x >> 6] = v;
  __syncthreads();
  float r = 0.0f;
  int nw = (int)(blockDim.x >> 6);
  if ((int)threadIdx.x < nw) r = scratch[threadIdx.x];
  #pragma unroll
  for (int o = 2; o > 0; o >>= 1) r += __shfl_down(r, o);
  return r;
}

// ---------- inverse norms of the 4 extra teacher frames (B*8192 rows) ----------
__global__ __launch_bounds__(256) void extra_norms_kernel(const float* __restrict__ tf,
                                                          float* __restrict__ invn) {
  __shared__ float scr[4];
  int row = blockIdx.x;                 // b*E + e
  int b = row >> 13, e = row & (E_DIM - 1);
  int fi = e >> 11, pe = e & (P_DIM - 1);
  const float* p = tf + ((size_t)(b * 8 + 1 + 2 * fi) * P_DIM + pe) * D_DIM;
  float4 v = *(const float4*)(p + threadIdx.x * 4);
  float s = block_reduce_sum(dot4(v, v), scr);
  if (threadIdx.x == 0) invn[row] = 1.0f / fmaxf(sqrtf(s), 1e-12f);
}

// ---------- sim = dot(ref_t, extra) * invn(extra); 128 x 8192 per batch ----------
__global__ __launch_bounds__(256) void sim_gemm_kernel(const float* __restrict__ tf,
                                                       const int* __restrict__ ref_perm,
                                                       const float* __restrict__ invn,
                                                       float* __restrict__ sim) {
  __shared__ float As[16][68];
  __shared__ float Bs[16][68];
  __shared__ const float* Arow[64];
  __shared__ const float* Brow[64];
  const int tid = threadIdx.x;
  const int b = blockIdx.z;
  const int mbase = blockIdx.y * 64;
  const int nbase = blockIdx.x * 64;
  if (tid < 64) {
    int m = mbase + tid;
    Arow[tid] = tf + ((size_t)(b * 8) * P_DIM + ref_perm[m]) * D_DIM;
  } else if (tid < 128) {
    int n = nbase + (tid - 64);
    int fi = n >> 11, pe = n & (P_DIM - 1);
    Brow[tid - 64] = tf + ((size_t)(b * 8 + 1 + 2 * fi) * P_DIM + pe) * D_DIM;
  }
  __syncthreads();
  const int lr = tid >> 2;
  const int lk = (tid & 3) * 4;
  const int m0 = (tid >> 4) * 4;
  const int n0 = (tid & 15) * 4;
  const float* arp = Arow[lr];
  const float* brp = Brow[lr];
  float acc[4][4] = {};
  for (int k0 = 0; k0 < D_DIM; k0 += 16) {
    float4 av = *(const float4*)(arp + k0 + lk);
    float4 bv = *(const float4*)(brp + k0 + lk);
    __syncthreads();
    As[lk + 0][lr] = av.x; As[lk + 1][lr] = av.y; As[lk + 2][lr] = av.z; As[lk + 3][lr] = av.w;
    Bs[lk + 0][lr] = bv.x; Bs[lk + 1][lr] = bv.y; Bs[lk + 2][lr] = bv.z; Bs[lk + 3][lr] = bv.w;
    __syncthreads();
    #pragma unroll
    for (int kk = 0; kk < 16; ++kk) {
      float4 a4 = *(const float4*)&As[kk][m0];
      float4 b4 = *(const float4*)&Bs[kk][n0];
      float a[4] = {a4.x, a4.y, a4.z, a4.w};
      float bb[4] = {b4.x, b4.y, b4.z, b4.w};
      #pragma unroll
      for (int i = 0; i < 4; ++i)
        #pragma unroll
        for (int j = 0; j < 4; ++j)
          acc[i][j] = fmaf(a[i], bb[j], acc[i][j]);
    }
  }
  float4 iv = *(const float4*)(invn + (size_t)b * E_DIM + nbase + n0);
  #pragma unroll
  for (int i = 0; i < 4; ++i) {
    int r = mbase + m0 + i;
    float4 o;
    o.x = acc[i][0] * iv.x; o.y = acc[i][1] * iv.y;
    o.z = acc[i][2] * iv.z; o.w = acc[i][3] * iv.w;
    *(float4*)(sim + ((size_t)(b * NR + r)) * E_DIM + nbase + n0) = o;
  }
}

// ---------- top-4 per sim row (only the index SET matters downstream) ----------
__global__ __launch_bounds__(256) void topk_kernel(const float* __restrict__ sim,
                                                   int* __restrict__ tki) {
  __shared__ float sv[1024];
  __shared__ int si[1024];
  int br = blockIdx.x;
  const float* row = sim + (size_t)br * E_DIM;
  float tv[4] = {-FLT_MAX, -FLT_MAX, -FLT_MAX, -FLT_MAX};
  int ti[4] = {INT_MAX, INT_MAX, INT_MAX, INT_MAX};
  for (int e = threadIdx.x; e < E_DIM; e += 256) {
    float x = row[e];
    if (better(x, e, tv[3], ti[3])) {
      tv[3] = x; ti[3] = e;
      #pragma unroll
      for (int k = 3; k > 0; --k) {
        if (better(tv[k], ti[k], tv[k - 1], ti[k - 1])) {
          float fv = tv[k]; tv[k] = tv[k - 1]; tv[k - 1] = fv;
          int fi2 = ti[k]; ti[k] = ti[k - 1]; ti[k - 1] = fi2;
        }
      }
    }
  }
  int t = threadIdx.x;
  #pragma unroll
  for (int k = 0; k < 4; ++k) { sv[t * 4 + k] = tv[k]; si[t * 4 + k] = ti[k]; }
  for (int stride = 128; stride > 0; stride >>= 1) {
    __syncthreads();
    if (t < stride) {
      float av[4], bv2[4]; int ai[4], bi2[4];
      #pragma unroll
      for (int k = 0; k < 4; ++k) {
        av[k] = sv[t * 4 + k];               ai[k] = si[t * 4 + k];
        bv2[k] = sv[(t + stride) * 4 + k];   bi2[k] = si[(t + stride) * 4 + k];
      }
      float ov[4]; int oi[4]; int pa = 0, pb = 0;
      #pragma unroll
      for (int k = 0; k < 4; ++k) {
        bool takeA = (pa < 4) && (pb >= 4 || better(av[pa], ai[pa], bv2[pb], bi2[pb]));
        if (takeA) { ov[k] = av[pa]; oi[k] = ai[pa]; ++pa; }
        else       { ov[k] = bv2[pb]; oi[k] = bi2[pb]; ++pb; }
      }
      #pragma unroll
      for (int k = 0; k < 4; ++k) { sv[t * 4 + k] = ov[k]; si[t * 4 + k] = oi[k]; }
    }
  }
  __syncthreads();
  if (t < 4) tki[br * 4 + t] = si[t];
}

// ---------- per-(b,r) tables: Rn2(t/s), Hn2, RH(t/s) ----------
__global__ __launch_bounds__(256) void tables_kernel(const float* __restrict__ tf,
                                                     const float* __restrict__ sf,
                                                     const int* __restrict__ ref_perm,
                                                     const int* __restrict__ tki,
                                                     float* __restrict__ rt_n2, float* __restrict__ rs_n2,
                                                     float* __restrict__ hn2,
                                                     float* __restrict__ rh_t, float* __restrict__ rh_s) {
  __shared__ float scr[4];
  int br = blockIdx.x;
  int b = br >> 7, r = br & 127;
  const float* rt = tf + ((size_t)(b * 8) * P_DIM + ref_perm[r]) * D_DIM;
  const float* rs = sf + ((size_t)(b * 4) * P_DIM + ref_perm[r]) * D_DIM;
  int j = threadIdx.x * 4;
  float4 vt = *(const float4*)(rt + j);
  float4 vs = *(const float4*)(rs + j);
  float red;
  red = block_reduce_sum(dot4(vt, vt), scr); if (threadIdx.x == 0) rt_n2[br] = red;
  red = block_reduce_sum(dot4(vs, vs), scr); if (threadIdx.x == 0) rs_n2[br] = red;
  for (int k = 0; k < KTOP; ++k) {
    int e = tki[br * KTOP + k];
    const float* hp = tf + ((size_t)(b * 8 + 1 + 2 * (e >> 11)) * P_DIM + (e & (P_DIM - 1))) * D_DIM;
    float4 vh = *(const float4*)(hp + j);
    red = block_reduce_sum(dot4(vh, vh), scr); if (threadIdx.x == 0) hn2[br * KTOP + k] = red;
    red = block_reduce_sum(dot4(vt, vh), scr); if (threadIdx.x == 0) rh_t[br * KTOP + k] = red;
    red = block_reduce_sum(dot4(vs, vh), scr); if (threadIdx.x == 0) rh_s[br * KTOP + k] = red;
  }
}

// ---------- Sh norms for 3 pairs, both sides ----------
__global__ __launch_bounds__(256) void sh_norms_kernel(const float* __restrict__ tf,
                                                       const float* __restrict__ sf,
                                                       const int* __restrict__ shared_perm,
                                                       float* __restrict__ shn2_t,
                                                       float* __restrict__ shn2_s) {
  __shared__ float scr[4];
  int row = blockIdx.x;                 // ((p*2 + b)*2 + side)*128 + s
  int s = row & 127;
  int side = (row >> 7) & 1;
  int b = (row >> 8) & 1;
  int p = row >> 9;
  const float* ptr = (side == 0)
      ? tf + ((size_t)(b * 8 + 2 * p + 2) * P_DIM + shared_perm[s]) * D_DIM
      : sf + ((size_t)(b * 4 + p + 1) * P_DIM + shared_perm[s]) * D_DIM;
  float4 v = *(const float4*)(ptr + threadIdx.x * 4);
  float red = block_reduce_sum(dot4(v, v), scr);
  if (threadIdx.x == 0) {
    float* dst = (side == 0) ? shn2_t : shn2_s;
    dst[(p * 2 + b) * NS + s] = red;
  }
}

// ---------- dense [ref_t; ref_s; H] x [Sh_t | Sh_s per pair] GEMM ----------
__global__ __launch_bounds__(256) void pair_gemm_kernel(const float* __restrict__ tf,
                                                        const float* __restrict__ sf,
                                                        const int* __restrict__ ref_perm,
                                                        const int* __restrict__ shared_perm,
                                                        const int* __restrict__ tki,
                                                        float* __restrict__ Cp) {
  __shared__ float As[16][68];
  __shared__ float Bs[16][68];
  __shared__ const float* Arow[64];
  __shared__ const float* Brow[64];
  const int tid = threadIdx.x;
  const int b = blockIdx.z;
  const int mbase = blockIdx.y * 64;
  const int nbase = blockIdx.x * 64;
  if (tid < 64) {
    int m = mbase + tid;
    const float* p;
    if (m < 128) {
      p = tf + ((size_t)(b * 8) * P_DIM + ref_perm[m]) * D_DIM;
    } else if (m < 256) {
      p = sf + ((size_t)(b * 4) * P_DIM + ref_perm[m - 128]) * D_DIM;
    } else {
      int h = m - 256, r = h >> 2, k = h & 3;
      int e = tki[(b * NR + r) * KTOP + k];
      p = tf + ((size_t)(b * 8 + 1 + 2 * (e >> 11)) * P_DIM + (e & (P_DIM - 1))) * D_DIM;
    }
    Arow[tid] = p;
  } else if (tid < 128) {
    int n = nbase + (tid - 64);
    int pr = n >> 8, rem = n & 255, side = rem >> 7, s = rem & 127;
    const float* p;
    if (side == 0) p = tf + ((size_t)(b * 8 + 2 * pr + 2) * P_DIM + shared_perm[s]) * D_DIM;
    else           p = sf + ((size_t)(b * 4 + pr + 1) * P_DIM + shared_perm[s]) * D_DIM;
    Brow[tid - 64] = p;
  }
  __syncthreads();
  const int lr = tid >> 2;
  const int lk = (tid & 3) * 4;
  const int m0 = (tid >> 4) * 4;
  const int n0 = (tid & 15) * 4;
  const float* arp = Arow[lr];
  const float* brp = Brow[lr];
  float acc[4][4] = {};
  for (int k0 = 0; k0 < D_DIM; k0 += 16) {
    float4 av = *(const float4*)(arp + k0 + lk);
    float4 bv = *(const float4*)(brp + k0 + lk);
    __syncthreads();
    As[lk + 0][lr] = av.x; As[lk + 1][lr] = av.y; As[lk + 2][lr] = av.z; As[lk + 3][lr] = av.w;
    Bs[lk + 0][lr] = bv.x; Bs[lk + 1][lr] = bv.y; Bs[lk + 2][lr] = bv.z; Bs[lk + 3][lr] = bv.w;
    __syncthreads();
    #pragma unroll
    for (int kk = 0; kk < 16; ++kk) {
      float4 a4 = *(const float4*)&As[kk][m0];
      float4 b4 = *(const float4*)&Bs[kk][n0];
      float a[4] = {a4.x, a4.y, a4.z, a4.w};
      float bb[4] = {b4.x, b4.y, b4.z, b4.w};
      #pragma unroll
      for (int i = 0; i < 4; ++i)
        #pragma unroll
        for (int j = 0; j < 4; ++j)
          acc[i][j] = fmaf(a[i], bb[j], acc[i][j]);
    }
  }
  #pragma unroll
  for (int i = 0; i < 4; ++i) {
    int m = mbase + m0 + i;
    float4 o = make_float4(acc[i][0], acc[i][1], acc[i][2], acc[i][3]);
    *(float4*)(Cp + ((size_t)b * M_PAIR + m) * N_PAIR + nbase + n0) = o;
  }
}

// ---------- angle + Huber reduction ----------
__global__ __launch_bounds__(128) void loss_kernel(const float* __restrict__ Cp,
                                                   const float* __restrict__ rt_n2,
                                                   const float* __restrict__ rs_n2,
                                                   const float* __restrict__ hn2,
                                                   const float* __restrict__ rh_t,
                                                   const float* __restrict__ rh_s,
                                                   const float* __restrict__ shn2_t,
                                                   const float* __restrict__ shn2_s,
                                                   float* __restrict__ acc) {
  __shared__ float scr[2];
  int r = blockIdx.x, b = blockIdx.y, p = blockIdx.z;
  int s = threadIdx.x;
  int br = b * NR + r;
  float Rt2 = rt_n2[br], Rs2 = rs_n2[br];
  float St2 = shn2_t[(p * 2 + b) * NS + s];
  float Ss2 = shn2_s[(p * 2 + b) * NS + s];
  const float* Cb = Cp + (size_t)b * M_PAIR * N_PAIR;
  float RSt = Cb[(size_t)r * N_PAIR + p * 256 + s];
  float RSs = Cb[(size_t)(128 + r) * N_PAIR + p * 256 + 128 + s];
  float sum = 0.0f;
  #pragma unroll
  for (int k = 0; k < KTOP; ++k) {
    float H2 = hn2[br * KTOP + k];
    float RHt = rh_t[br * KTOP + k];
    float RHs = rh_s[br * KTOP + k];
    const float* hrow = Cb + (size_t)(256 + (r * 4 + k)) * N_PAIR + p * 256;
    float HSt = hrow[s];
    float HSs = hrow[128 + s];
    // teacher angles
    float nRSt = fmaxf(sqrtf(fmaxf(Rt2 + St2 - 2.0f * RSt, 0.0f)), ANG_EPS);
    float nRHt = fmaxf(sqrtf(fmaxf(Rt2 + H2 - 2.0f * RHt, 0.0f)), ANG_EPS);
    float nHSt = fmaxf(sqrtf(fmaxf(H2 + St2 - 2.0f * HSt, 0.0f)), ANG_EPS);
    float a1t = (HSt - RSt - RHt + Rt2) / (nRSt * nRHt);
    float a2t = (RSt - RHt - HSt + H2) / (nRHt * nHSt);
    float a3t = (RHt - RSt - HSt + St2) / (nRSt * nHSt);
    // student angles (H shared)
    float nRSs = fmaxf(sqrtf(fmaxf(Rs2 + Ss2 - 2.0f * RSs, 0.0f)), ANG_EPS);
    float nRHs = fmaxf(sqrtf(fmaxf(Rs2 + H2 - 2.0f * RHs, 0.0f)), ANG_EPS);
    float nHSs = fmaxf(sqrtf(fmaxf(H2 + Ss2 - 2.0f * HSs, 0.0f)), ANG_EPS);
    float a1s = (HSs - RSs - RHs + Rs2) / (nRSs * nRHs);
    float a2s = (RSs - RHs - HSs + H2) / (nRHs * nHSs);
    float a3s = (RHs - RSs - HSs + Ss2) / (nRSs * nHSs);
    sum += huber(a1s - a1t) + huber(a2s - a2t) + huber(a3s - a3t);
  }
  float tot = block_reduce_sum(sum, scr);
  if (threadIdx.x == 0) atomicAdd(acc, tot);
}

__global__ void finalize_kernel(const float* __restrict__ acc, float* __restrict__ out) {
  if (threadIdx.x == 0 && blockIdx.x == 0)
    out[0] = acc[0] * (1.0f / 393216.0f);   // 3 * B * NR * NS * KTOP
}

extern "C" void kernel_launch(void* const* d_in, const int* in_sizes, int n_in,
                              void* d_out, int out_size, void* d_ws, size_t ws_size,
                              hipStream_t stream) {
  const float* tf = (const float*)d_in[0];
  const float* sf = (const float*)d_in[1];
  const int* ref_perm = (const int*)d_in[2];
  const int* shared_perm = (const int*)d_in[3];
  float* ws = (float*)d_ws;

  float* sim    = ws;                                   // 2*128*8192   = 2097152
  float* Cp     = sim    + (size_t)NB * NR * E_DIM;     // 2*768*768    = 1179648
  float* invn   = Cp     + (size_t)NB * M_PAIR * N_PAIR;// 16384
  float* rt_n2  = invn   + (size_t)NB * E_DIM;          // 256
  float* rs_n2  = rt_n2  + NB * NR;                     // 256
  float* hn2    = rs_n2  + NB * NR;                     // 1024
  float* rh_t   = hn2    + NB * NR * KTOP;              // 1024
  float* rh_s   = rh_t   + NB * NR * KTOP;              // 1024
  float* shn2_t = rh_s   + NB * NR * KTOP;              // 768
  float* shn2_s = shn2_t + 3 * NB * NS;                 // 768
  float* acc    = shn2_s + 3 * NB * NS;                 // 4 (padded)
  int*   tki    = (int*)(acc + 4);                      // 1024 ints
  float* out = (float*)d_out;

  hipMemsetAsync(acc, 0, sizeof(float), stream);
  extra_norms_kernel<<<NB * E_DIM, 256, 0, stream>>>(tf, invn);
  sim_gemm_kernel<<<dim3(E_DIM / 64, NR / 64, NB), 256, 0, stream>>>(tf, ref_perm, invn, sim);
  topk_kernel<<<NB * NR, 256, 0, stream>>>(sim, tki);
  tables_kernel<<<NB * NR, 256, 0, stream>>>(tf, sf, ref_perm, tki, rt_n2, rs_n2, hn2, rh_t, rh_s);
  sh_norms_kernel<<<3 * NB * 2 * NS, 256, 0, stream>>>(tf, sf, shared_perm, shn2_t, shn2_s);
  pair_gemm_kernel<<<dim3(N_PAIR / 64, M_PAIR / 64, NB), 256, 0, stream>>>(tf, sf, ref_perm, shared_perm, tki, Cp);
  loss_kernel<<<dim3(NR, NB, 3), 128, 0, stream>>>(Cp, rt_n2, rs_n2, hn2, rh_t, rh_s, shn2_t, shn2_s, acc);
  finalize_kernel<<<1, 64, 0, stream>>>(acc, out);
}